// Round 2
// baseline (336.832 us; speedup 1.0000x reference)
//
#include <hip/hip_runtime.h>

#define NQ     12
#define NPARAM 240       // 12*4*5
#define BLOCK  64

// State layout: global index g[11:0]; lane = g[11:6], register index r = g[5:0].
// Qubit q sits at bit position P = 11 - q (q=0 is the MSB axis in the reference).
// P < 6  -> register-class gate (static in-lane pairs)
// P >= 6 -> lane-class gate (shfl_xor with partner lane)

template<int P>
__device__ __forceinline__ void apply1q(float2* st, int lane, const float* m) {
    float u00x=m[0],u00y=m[1],u01x=m[2],u01y=m[3];
    float u10x=m[4],u10y=m[5],u11x=m[6],u11y=m[7];
    if constexpr (P < 6) {
        #pragma unroll
        for (int r = 0; r < 64; ++r) {
            if ((r >> P) & 1) continue;
            int r1 = r | (1 << P);
            float2 s0 = st[r], s1 = st[r1];
            st[r]  = make_float2(u00x*s0.x - u00y*s0.y + u01x*s1.x - u01y*s1.y,
                                 u00x*s0.y + u00y*s0.x + u01x*s1.y + u01y*s1.x);
            st[r1] = make_float2(u10x*s0.x - u10y*s0.y + u11x*s1.x - u11y*s1.y,
                                 u10x*s0.y + u10y*s0.x + u11x*s1.y + u11y*s1.x);
        }
    } else {
        constexpr int LM = 1 << (P - 6);
        int bit = (lane >> (P - 6)) & 1;
        // self coeff = diag entry, other coeff = off-diag entry for this side
        float uax = bit ? u11x : u00x, uay = bit ? u11y : u00y;
        float ubx = bit ? u10x : u01x, uby = bit ? u10y : u01y;
        #pragma unroll
        for (int r = 0; r < 64; ++r) {
            float sx = st[r].x, sy = st[r].y;
            float ox = __shfl_xor(sx, LM, 64);
            float oy = __shfl_xor(sy, LM, 64);
            st[r] = make_float2(uax*sx - uay*sy + ubx*ox - uby*oy,
                                uax*sy + uay*sx + ubx*oy + uby*ox);
        }
    }
}

// CRX(ctrl at bit PC, tgt at bit PT): on ctrl=1 half, RX: n = c*s - i*sin*partner
template<int PC, int PT>
__device__ __forceinline__ void applyCRX(float2* st, int lane, const float* cs) {
    float c = cs[0], s = cs[1];
    if constexpr (PT < 6) {
        if constexpr (PC < 6) {
            #pragma unroll
            for (int r = 0; r < 64; ++r) {
                if (!((r >> PC) & 1) || ((r >> PT) & 1)) continue;
                int r1 = r | (1 << PT);
                float2 s0 = st[r], s1 = st[r1];
                st[r]  = make_float2(c*s0.x + s*s1.y, c*s0.y - s*s1.x);
                st[r1] = make_float2(c*s1.x + s*s0.y, c*s1.y - s*s0.x);
            }
        } else {
            int apply = (lane >> (PC - 6)) & 1;
            float cc = apply ? c : 1.0f;
            float ss = apply ? s : 0.0f;
            #pragma unroll
            for (int r = 0; r < 64; ++r) {
                if ((r >> PT) & 1) continue;
                int r1 = r | (1 << PT);
                float2 s0 = st[r], s1 = st[r1];
                st[r]  = make_float2(cc*s0.x + ss*s1.y, cc*s0.y - ss*s1.x);
                st[r1] = make_float2(cc*s1.x + ss*s0.y, cc*s1.y - ss*s0.x);
            }
        }
    } else {
        constexpr int LM = 1 << (PT - 6);
        if constexpr (PC < 6) {
            // RX is symmetric: both sides do n = c*self - i*s*other
            #pragma unroll
            for (int r = 0; r < 64; ++r) {
                if (!((r >> PC) & 1)) continue;
                float sx = st[r].x, sy = st[r].y;
                float ox = __shfl_xor(sx, LM, 64);
                float oy = __shfl_xor(sy, LM, 64);
                st[r] = make_float2(c*sx + s*oy, c*sy - s*ox);
            }
        } else {
            int apply = (lane >> (PC - 6)) & 1;
            float cc = apply ? c : 1.0f;
            float ss = apply ? s : 0.0f;
            #pragma unroll
            for (int r = 0; r < 64; ++r) {
                float sx = st[r].x, sy = st[r].y;
                float ox = __shfl_xor(sx, LM, 64);
                float oy = __shfl_xor(sy, LM, 64);
                st[r] = make_float2(cc*sx + ss*oy, cc*sy - ss*ox);
            }
        }
    }
}

template<int P>
__device__ __forceinline__ void expectq(const float2* st, int lane,
                                        float& X, float& Y, float& Z) {
    float lx = 0.f, ly = 0.f, lz = 0.f;
    if constexpr (P < 6) {
        #pragma unroll
        for (int r = 0; r < 64; ++r) {
            float2 a = st[r];
            float n = a.x*a.x + a.y*a.y;
            lz += ((r >> P) & 1) ? -n : n;
        }
        #pragma unroll
        for (int r = 0; r < 64; ++r) {
            if ((r >> P) & 1) continue;
            int r1 = r | (1 << P);
            float2 s0 = st[r], s1 = st[r1];
            lx += s0.x*s1.x + s0.y*s1.y;
            ly += s0.x*s1.y - s0.y*s1.x;
        }
    } else {
        constexpr int LM = 1 << (P - 6);
        int bit = (lane >> (P - 6)) & 1;
        float zs = bit ? -1.f : 1.f;
        float m  = bit ?  0.f : 1.f;    // only bit=0 lanes accumulate offdiag
        #pragma unroll
        for (int r = 0; r < 64; ++r) {
            float2 a = st[r];
            lz += zs * (a.x*a.x + a.y*a.y);
            float ox = __shfl_xor(a.x, LM, 64);
            float oy = __shfl_xor(a.y, LM, 64);
            lx += m * (a.x*ox + a.y*oy);
            ly += m * (a.x*oy - a.y*ox);
        }
    }
    #pragma unroll
    for (int off = 32; off; off >>= 1) {
        lx += __shfl_xor(lx, off, 64);
        ly += __shfl_xor(ly, off, 64);
        lz += __shfl_xor(lz, off, 64);
    }
    X = 2.f*lx; Y = 2.f*ly; Z = lz;
}

__device__ __forceinline__ float2 cmulf(float2 a, float2 b) {
    return make_float2(a.x*b.x - a.y*b.y, a.x*b.y + a.y*b.x);
}

__global__ __launch_bounds__(BLOCK, 1)
void qfe_kernel(const float* __restrict__ params,
                const float* __restrict__ inputs,
                float* __restrict__ out) {
    const int b = blockIdx.x;
    const int lane = threadIdx.x;

    // m1[slot][qubit][8]: slot 0 = RY embed, slots 1..4 = fused Rz*Ry*Rx
    __shared__ float m1[5 * 12 * 8];
    __shared__ float mcrx[4 * 24 * 2];

    if (lane < 12) {
        float a = inputs[b * NQ + lane] * 0.5f;
        float c = cosf(a), s = sinf(a);
        float* m = &m1[lane * 8];
        m[0]=c; m[1]=0.f; m[2]=-s; m[3]=0.f; m[4]=s; m[5]=0.f; m[6]=c; m[7]=0.f;
    }
    if (lane < 48) {
        int l = lane / 12, q = lane % 12;
        const float* pp = params + b * NPARAM + l * 60 + q * 3;
        float ax = pp[0]*0.5f, ay = pp[1]*0.5f, az = pp[2]*0.5f;
        float cx = cosf(ax), sx = sinf(ax);
        float cy = cosf(ay), sy = sinf(ay);
        float cz = cosf(az), sz = sinf(az);
        float2 a00 = make_float2( cy*cx,  sy*sx);
        float2 a01 = make_float2(-sy*cx, -cy*sx);
        float2 a10 = make_float2( sy*cx, -cy*sx);
        float2 a11 = make_float2( cy*cx, -sy*sx);
        float2 e0 = make_float2(cz, -sz);
        float2 e1 = make_float2(cz,  sz);
        float2 u00 = cmulf(e0, a00), u01 = cmulf(e0, a01);
        float2 u10 = cmulf(e1, a10), u11 = cmulf(e1, a11);
        float* m = &m1[((l + 1) * 12 + q) * 8];
        m[0]=u00.x; m[1]=u00.y; m[2]=u01.x; m[3]=u01.y;
        m[4]=u10.x; m[5]=u10.y; m[6]=u11.x; m[7]=u11.y;
    }
    for (int j = lane; j < 96; j += 64) {
        int l = j / 24, k = j % 24;
        float a = params[b * NPARAM + l * 60 + 36 + k] * 0.5f;
        mcrx[(l * 24 + k) * 2]     = cosf(a);
        mcrx[(l * 24 + k) * 2 + 1] = sinf(a);
    }
    __syncthreads();

    float2 st[64];
    #pragma unroll
    for (int r = 0; r < 64; ++r) st[r] = make_float2(0.f, 0.f);
    if (lane == 0) st[0] = make_float2(1.f, 0.f);

#define APPLY1Q(q) apply1q<11 - (q)>(st, lane, ml + (q) * 8);
// ring1 step j: ctrl q=j (PC=11-j), tgt q=(j+1)%12 (PT=11-((j+1)%12)), params idx j
#define R1(j) applyCRX<11 - (j), (11 - (((j) + 1) % 12))>(st, lane, cl + (j) * 2);
// ring2 step k: ctrl q=11-k (PC=k), tgt q=(10-k)%12 (PT=11-((22-k)%12)), params idx 12+k
#define R2(k) applyCRX<(k), (11 - ((22 - (k)) % 12))>(st, lane, cl + (12 + (k)) * 2);

    for (int l = 0; l < 5; ++l) {
        const float* ml = m1 + l * 96;
        APPLY1Q(0)  APPLY1Q(1)  APPLY1Q(2)  APPLY1Q(3)
        APPLY1Q(4)  APPLY1Q(5)  APPLY1Q(6)  APPLY1Q(7)
        APPLY1Q(8)  APPLY1Q(9)  APPLY1Q(10) APPLY1Q(11)
        if (l > 0) {
            const float* cl = mcrx + (l - 1) * 48;
            R1(0)  R1(1)  R1(2)  R1(3)  R1(4)  R1(5)
            R1(6)  R1(7)  R1(8)  R1(9)  R1(10) R1(11)
            R2(0)  R2(1)  R2(2)  R2(3)  R2(4)  R2(5)
            R2(6)  R2(7)  R2(8)  R2(9)  R2(10) R2(11)
        }
    }

    float* ob = out + b * 36;
#define EXPECT(q) { float X, Y, Z; expectq<11 - (q)>(st, lane, X, Y, Z); \
                    if (lane == 0) { ob[(q)] = X; ob[12 + (q)] = Y; ob[24 + (q)] = Z; } }
    EXPECT(0)  EXPECT(1)  EXPECT(2)  EXPECT(3)
    EXPECT(4)  EXPECT(5)  EXPECT(6)  EXPECT(7)
    EXPECT(8)  EXPECT(9)  EXPECT(10) EXPECT(11)
}

extern "C" void kernel_launch(void* const* d_in, const int* in_sizes, int n_in,
                              void* d_out, int out_size, void* d_ws, size_t ws_size,
                              hipStream_t stream) {
    const float* params = (const float*)d_in[0];   // (1024, 240) float32
    const float* inputs = (const float*)d_in[1];   // (1024, 12)  float32
    float* out = (float*)d_out;                    // (1024, 36)  float32
    qfe_kernel<<<1024, BLOCK, 0, stream>>>(params, inputs, out);
}

// Round 3
// 231.608 us; speedup vs baseline: 1.4543x; 1.4543x over previous
//
#include <hip/hip_runtime.h>

#define NQ     12
#define NPARAM 240       // 12*4*5
#define BLOCK  128
#define NREG   32

// State layout: global index g[11:0]; qubit q sits at bit P = 11 - q.
//   g[4:0]  = register index r (st[32] per lane, 64 VGPRs)
//   g[10:5] = lane index within wave
//   g[11]   = wave index w (2 waves per block)
// P < 5   -> register-class gate (static in-lane pairs)
// 5<=P<11 -> lane-class gate (shfl_xor)
// P == 11 -> wave-class gate (LDS exchange, conflict-free buf[r][tid])

__device__ __forceinline__ float2 cmulf(float2 a, float2 b) {
    return make_float2(a.x*b.x - a.y*b.y, a.x*b.y + a.y*b.x);
}

template<int P>
__device__ __forceinline__ void apply1q(float2* st, int lane, int w, int tid,
                                        float2 (*buf)[BLOCK], const float* m) {
    float u00x=m[0],u00y=m[1],u01x=m[2],u01y=m[3];
    float u10x=m[4],u10y=m[5],u11x=m[6],u11y=m[7];
    if constexpr (P < 5) {
        #pragma unroll
        for (int r = 0; r < NREG; ++r) {
            if ((r >> P) & 1) continue;
            int r1 = r | (1 << P);
            float2 s0 = st[r], s1 = st[r1];
            st[r]  = make_float2(u00x*s0.x - u00y*s0.y + u01x*s1.x - u01y*s1.y,
                                 u00x*s0.y + u00y*s0.x + u01x*s1.y + u01y*s1.x);
            st[r1] = make_float2(u10x*s0.x - u10y*s0.y + u11x*s1.x - u11y*s1.y,
                                 u10x*s0.y + u10y*s0.x + u11x*s1.y + u11y*s1.x);
        }
    } else if constexpr (P < 11) {
        constexpr int LM = 1 << (P - 5);
        int bit = (lane >> (P - 5)) & 1;
        float uax = bit ? u11x : u00x, uay = bit ? u11y : u00y;
        float ubx = bit ? u10x : u01x, uby = bit ? u10y : u01y;
        #pragma unroll
        for (int r = 0; r < NREG; ++r) {
            float sx = st[r].x, sy = st[r].y;
            float ox = __shfl_xor(sx, LM, 64);
            float oy = __shfl_xor(sy, LM, 64);
            st[r] = make_float2(uax*sx - uay*sy + ubx*ox - uby*oy,
                                uax*sy + uay*sx + ubx*oy + uby*ox);
        }
    } else {
        float uax = w ? u11x : u00x, uay = w ? u11y : u00y;
        float ubx = w ? u10x : u01x, uby = w ? u10y : u01y;
        __syncthreads();                       // WAR: prior buf reads done
        #pragma unroll
        for (int r = 0; r < NREG; ++r) buf[r][tid] = st[r];
        __syncthreads();
        int pt = tid ^ 64;
        #pragma unroll
        for (int r = 0; r < NREG; ++r) {
            float2 o = buf[r][pt];
            float sx = st[r].x, sy = st[r].y;
            st[r] = make_float2(uax*sx - uay*sy + ubx*o.x - uby*o.y,
                                uax*sy + uay*sx + ubx*o.y + uby*o.x);
        }
    }
}

// CRX(ctrl bit PC, tgt bit PT): on ctrl=1 subspace apply RX: n = c*self - i*s*other
template<int PC, int PT>
__device__ __forceinline__ void applyCRX(float2* st, int lane, int w, int tid,
                                         float2 (*buf)[BLOCK], const float* cs) {
    float c = cs[0], s = cs[1];
    if constexpr (PT < 5) {
        if constexpr (PC < 5) {
            #pragma unroll
            for (int r = 0; r < NREG; ++r) {
                if (!((r >> PC) & 1) || ((r >> PT) & 1)) continue;
                int r1 = r | (1 << PT);
                float2 s0 = st[r], s1 = st[r1];
                st[r]  = make_float2(c*s0.x + s*s1.y, c*s0.y - s*s1.x);
                st[r1] = make_float2(c*s1.x + s*s0.y, c*s1.y - s*s0.x);
            }
        } else if constexpr (PC < 11) {
            int apply = (lane >> (PC - 5)) & 1;
            float cc = apply ? c : 1.0f, ss = apply ? s : 0.0f;
            #pragma unroll
            for (int r = 0; r < NREG; ++r) {
                if ((r >> PT) & 1) continue;
                int r1 = r | (1 << PT);
                float2 s0 = st[r], s1 = st[r1];
                st[r]  = make_float2(cc*s0.x + ss*s1.y, cc*s0.y - ss*s1.x);
                st[r1] = make_float2(cc*s1.x + ss*s0.y, cc*s1.y - ss*s0.x);
            }
        } else {
            float cc = w ? c : 1.0f, ss = w ? s : 0.0f;
            #pragma unroll
            for (int r = 0; r < NREG; ++r) {
                if ((r >> PT) & 1) continue;
                int r1 = r | (1 << PT);
                float2 s0 = st[r], s1 = st[r1];
                st[r]  = make_float2(cc*s0.x + ss*s1.y, cc*s0.y - ss*s1.x);
                st[r1] = make_float2(cc*s1.x + ss*s0.y, cc*s1.y - ss*s0.x);
            }
        }
    } else if constexpr (PT < 11) {
        constexpr int LM = 1 << (PT - 5);
        if constexpr (PC < 5) {
            // ctrl in register bits: partner has same r; inactive r untouched
            #pragma unroll
            for (int r = 0; r < NREG; ++r) {
                if (!((r >> PC) & 1)) continue;
                float sx = st[r].x, sy = st[r].y;
                float ox = __shfl_xor(sx, LM, 64);
                float oy = __shfl_xor(sy, LM, 64);
                st[r] = make_float2(c*sx + s*oy, c*sy - s*ox);
            }
        } else if constexpr (PC < 11) {
            int apply = (lane >> (PC - 5)) & 1;
            float cc = apply ? c : 1.0f, ss = apply ? s : 0.0f;
            #pragma unroll
            for (int r = 0; r < NREG; ++r) {
                float sx = st[r].x, sy = st[r].y;
                float ox = __shfl_xor(sx, LM, 64);
                float oy = __shfl_xor(sy, LM, 64);
                st[r] = make_float2(cc*sx + ss*oy, cc*sy - ss*ox);
            }
        } else {
            float cc = w ? c : 1.0f, ss = w ? s : 0.0f;
            #pragma unroll
            for (int r = 0; r < NREG; ++r) {
                float sx = st[r].x, sy = st[r].y;
                float ox = __shfl_xor(sx, LM, 64);
                float oy = __shfl_xor(sy, LM, 64);
                st[r] = make_float2(cc*sx + ss*oy, cc*sy - ss*ox);
            }
        }
    } else {
        // PT == 11: LDS exchange; partner = other wave, same lane, same r
        if constexpr (PC < 5) {
            __syncthreads();
            #pragma unroll
            for (int r = 0; r < NREG; ++r)
                if ((r >> PC) & 1) buf[r][tid] = st[r];
            __syncthreads();
            int pt = tid ^ 64;
            #pragma unroll
            for (int r = 0; r < NREG; ++r) {
                if (!((r >> PC) & 1)) continue;
                float2 o = buf[r][pt];
                st[r] = make_float2(c*st[r].x + s*o.y, c*st[r].y - s*o.x);
            }
        } else {
            int apply = (lane >> (PC - 5)) & 1;
            float cc = apply ? c : 1.0f, ss = apply ? s : 0.0f;
            __syncthreads();
            #pragma unroll
            for (int r = 0; r < NREG; ++r) buf[r][tid] = st[r];
            __syncthreads();
            int pt = tid ^ 64;
            #pragma unroll
            for (int r = 0; r < NREG; ++r) {
                float2 o = buf[r][pt];
                st[r] = make_float2(cc*st[r].x + ss*o.y, cc*st[r].y - ss*o.x);
            }
        }
    }
}

template<int P>
__device__ __forceinline__ void expectq(const float2* st, int lane, int w, int tid,
                                        float2 (*buf)[BLOCK],
                                        float& X, float& Y, float& Z) {
    float lx = 0.f, ly = 0.f, lz = 0.f;
    if constexpr (P < 5) {
        #pragma unroll
        for (int r = 0; r < NREG; ++r) {
            float2 a = st[r];
            float n = a.x*a.x + a.y*a.y;
            lz += ((r >> P) & 1) ? -n : n;
        }
        #pragma unroll
        for (int r = 0; r < NREG; ++r) {
            if ((r >> P) & 1) continue;
            int r1 = r | (1 << P);
            float2 s0 = st[r], s1 = st[r1];
            lx += s0.x*s1.x + s0.y*s1.y;
            ly += s0.x*s1.y - s0.y*s1.x;
        }
    } else if constexpr (P < 11) {
        constexpr int LM = 1 << (P - 5);
        int bit = (lane >> (P - 5)) & 1;
        float zs = bit ? -1.f : 1.f;
        float m  = bit ?  0.f : 1.f;
        #pragma unroll
        for (int r = 0; r < NREG; ++r) {
            float2 a = st[r];
            lz += zs * (a.x*a.x + a.y*a.y);
            float ox = __shfl_xor(a.x, LM, 64);
            float oy = __shfl_xor(a.y, LM, 64);
            lx += m * (a.x*ox + a.y*oy);
            ly += m * (a.x*oy - a.y*ox);
        }
    } else {
        float zs = w ? -1.f : 1.f;
        float m  = w ?  0.f : 1.f;
        __syncthreads();
        #pragma unroll
        for (int r = 0; r < NREG; ++r) buf[r][tid] = st[r];
        __syncthreads();
        int pt = tid ^ 64;
        #pragma unroll
        for (int r = 0; r < NREG; ++r) {
            float2 a = st[r];
            lz += zs * (a.x*a.x + a.y*a.y);
            float2 o = buf[r][pt];
            lx += m * (a.x*o.x + a.y*o.y);
            ly += m * (a.x*o.y - a.y*o.x);
        }
    }
    #pragma unroll
    for (int off = 32; off; off >>= 1) {
        lx += __shfl_xor(lx, off, 64);
        ly += __shfl_xor(ly, off, 64);
        lz += __shfl_xor(lz, off, 64);
    }
    X = 2.f*lx; Y = 2.f*ly; Z = lz;
}

__global__ __launch_bounds__(BLOCK, 2)
void qfe_kernel(const float* __restrict__ params,
                const float* __restrict__ inputs,
                float* __restrict__ out) {
    const int b    = blockIdx.x;
    const int tid  = threadIdx.x;
    const int lane = tid & 63;
    const int w    = tid >> 6;

    __shared__ float2 buf[NREG][BLOCK];   // 32 KB exchange buffer, conflict-free
    __shared__ float  m1[4 * 12 * 8];     // fused (Rz*Ry*Rx [*RYembed]) matrices
    __shared__ float  mcrx[4 * 24 * 2];
    __shared__ float  redbuf[2][36];

    if (tid < 48) {
        int l = tid / 12, q = tid % 12;
        const float* pp = params + b * NPARAM + l * 60 + q * 3;
        float ax = pp[0]*0.5f, ay = pp[1]*0.5f, az = pp[2]*0.5f;
        float cx = cosf(ax), sx = sinf(ax);
        float cy = cosf(ay), sy = sinf(ay);
        float cz = cosf(az), sz = sinf(az);
        float2 a00 = make_float2( cy*cx,  sy*sx);
        float2 a01 = make_float2(-sy*cx, -cy*sx);
        float2 a10 = make_float2( sy*cx, -cy*sx);
        float2 a11 = make_float2( cy*cx, -sy*sx);
        float2 e0 = make_float2(cz, -sz);
        float2 e1 = make_float2(cz,  sz);
        float2 u00 = cmulf(e0, a00), u01 = cmulf(e0, a01);
        float2 u10 = cmulf(e1, a10), u11 = cmulf(e1, a11);
        if (l == 0) {
            // fold RY input embedding: U = (Rz Ry Rx) * RY(e)
            float e = inputs[b * NQ + q] * 0.5f;
            float ce = cosf(e), se = sinf(e);
            float2 v00 = make_float2(u00.x*ce + u01.x*se, u00.y*ce + u01.y*se);
            float2 v01 = make_float2(-u00.x*se + u01.x*ce, -u00.y*se + u01.y*ce);
            float2 v10 = make_float2(u10.x*ce + u11.x*se, u10.y*ce + u11.y*se);
            float2 v11 = make_float2(-u10.x*se + u11.x*ce, -u10.y*se + u11.y*ce);
            u00 = v00; u01 = v01; u10 = v10; u11 = v11;
        }
        float* m = &m1[(l * 12 + q) * 8];
        m[0]=u00.x; m[1]=u00.y; m[2]=u01.x; m[3]=u01.y;
        m[4]=u10.x; m[5]=u10.y; m[6]=u11.x; m[7]=u11.y;
    }
    if (tid < 96) {
        int l = tid / 24, k = tid % 24;
        float a = params[b * NPARAM + l * 60 + 36 + k] * 0.5f;
        mcrx[(l * 24 + k) * 2]     = cosf(a);
        mcrx[(l * 24 + k) * 2 + 1] = sinf(a);
    }
    __syncthreads();

    float2 st[NREG];
    #pragma unroll
    for (int r = 0; r < NREG; ++r) st[r] = make_float2(0.f, 0.f);
    if (tid == 0) st[0] = make_float2(1.f, 0.f);

#define APPLY1Q(q) apply1q<11 - (q)>(st, lane, w, tid, buf, ml + (q) * 8);
#define R1(j) applyCRX<11 - (j), (11 - (((j) + 1) % 12))>(st, lane, w, tid, buf, cl + (j) * 2);
#define R2(k) applyCRX<(k), (11 - ((22 - (k)) % 12))>(st, lane, w, tid, buf, cl + (12 + (k)) * 2);

    #pragma unroll 1
    for (int l = 0; l < 4; ++l) {
        const float* ml = m1 + l * 96;
        const float* cl = mcrx + l * 48;
        APPLY1Q(0)  APPLY1Q(1)  APPLY1Q(2)  APPLY1Q(3)
        APPLY1Q(4)  APPLY1Q(5)  APPLY1Q(6)  APPLY1Q(7)
        APPLY1Q(8)  APPLY1Q(9)  APPLY1Q(10) APPLY1Q(11)
        R1(0)  R1(1)  R1(2)  R1(3)  R1(4)  R1(5)
        R1(6)  R1(7)  R1(8)  R1(9)  R1(10) R1(11)
        R2(0)  R2(1)  R2(2)  R2(3)  R2(4)  R2(5)
        R2(6)  R2(7)  R2(8)  R2(9)  R2(10) R2(11)
    }

#define EXPECT(q) { float X, Y, Z; expectq<11 - (q)>(st, lane, w, tid, buf, X, Y, Z); \
                    if (lane == 0) { redbuf[w][(q)] = X; redbuf[w][12 + (q)] = Y; redbuf[w][24 + (q)] = Z; } }
    EXPECT(0)  EXPECT(1)  EXPECT(2)  EXPECT(3)
    EXPECT(4)  EXPECT(5)  EXPECT(6)  EXPECT(7)
    EXPECT(8)  EXPECT(9)  EXPECT(10) EXPECT(11)
    __syncthreads();
    if (tid < 36) out[b * 36 + tid] = redbuf[0][tid] + redbuf[1][tid];
}

extern "C" void kernel_launch(void* const* d_in, const int* in_sizes, int n_in,
                              void* d_out, int out_size, void* d_ws, size_t ws_size,
                              hipStream_t stream) {
    const float* params = (const float*)d_in[0];   // (1024, 240) float32
    const float* inputs = (const float*)d_in[1];   // (1024, 12)  float32
    float* out = (float*)d_out;                    // (1024, 36)  float32
    qfe_kernel<<<1024, BLOCK, 0, stream>>>(params, inputs, out);
}